// Round 5
// baseline (835.359 us; speedup 1.0000x reference)
//
#include <hip/hip_runtime.h>
#include <hip/hip_fp16.h>

#define BB    8
#define NPTS  4096
#define SS    1024
#define KK    128
#define CAP   512
#define NW    248          // worker blocks (8 + 248 = 256 = #CUs)
#define TPB   256
#define PPT   16

typedef _Float16 half8 __attribute__((ext_vector_type(8)));
typedef float    f32x4 __attribute__((ext_vector_type(4)));

// ---------------------------------------------------------------------------
// Fused streaming kernel, R5: dedicated-CU placement.
//   LDS is padded to 84 KiB -> exactly ONE block per CU (160/84). Grid = 256
//   blocks = #CUs, so every block owns a CU: FPS blocks (0..7) run at their
//   measured solo pace (564us) with zero intra-CU interference from workers.
//   R4 measured the 2-blocks/CU co-residency stretching FPS 564->766us
//   (VALU-slot + LDS-port contention); this removes it.
//   FPS blocks  : R2-proven loop, publish prog[cloud] every 64 iters
//                 (agent-release).
//   Worker blocks: E -> (release ectr) -> stage W in LDS -> (acquire ectr)
//                 -> per group {acquire prog; ball -> LDS nbr; mlp x4}.
// Dependencies acyclic; FPS waits on nothing, so even partial residency
// drains (FPS completion frees CUs).
// ---------------------------------------------------------------------------

struct __align__(16) FpsSm {
    float4 Pl[NPTS];                       // 64 KB point cache
    unsigned long long wkey[2][4];         // parity-double-buffered
};
struct __align__(16) WkSm {
    float cd2[4][CAP];
    int   cidx[4][CAP];
    int   nbrL[4][KK];                     // neighbor ids (global), LDS-only
    _Float16 W2t[64 * 64];                 // [n][k] swizzled
    _Float16 W3t[128 * 64];                // [n][k] swizzled
    _Float16 h2buf[4][32 * 64];
    float csh[64];
    float cpart[4][128];
    float b2s[64];
    float b3s[128];
};
union __align__(16) SMem {
    FpsSm f;
    WkSm  w;
    char  pad[84 * 1024];                  // force 1 block/CU (160KB LDS / 84KB)
};

__device__ __forceinline__ void st_rel(unsigned* p, unsigned v) {
    __hip_atomic_store(p, v, __ATOMIC_RELEASE, __HIP_MEMORY_SCOPE_AGENT);
}
__device__ __forceinline__ unsigned ld_acq(unsigned* p) {
    return __hip_atomic_load(p, __ATOMIC_ACQUIRE, __HIP_MEMORY_SCOPE_AGENT);
}

// one DPP fmax step (old preserved on disabled lanes => identity for max)
#define DPP_FMAX(CTRL)                                                                  \
    {                                                                                   \
        unsigned o = (unsigned)__builtin_amdgcn_update_dpp(                             \
            (int)__float_as_uint(m), (int)__float_as_uint(m), CTRL, 0xF, 0xF, false);   \
        m = fmaxf(m, __uint_as_float(o));                                               \
    }

__global__ __launch_bounds__(TPB) void fused_kernel(const float* __restrict__ pos,
                                                    const int* __restrict__ batch,
                                                    const float* __restrict__ x,
                                                    const float* __restrict__ W1,
                                                    const float* __restrict__ b1,
                                                    const float* __restrict__ W2,
                                                    const float* __restrict__ b2,
                                                    const float* __restrict__ W3,
                                                    const float* __restrict__ b3,
                                                    float* __restrict__ E,
                                                    float* __restrict__ pos_out,
                                                    float* __restrict__ batch_out,
                                                    float* __restrict__ xout,
                                                    unsigned* __restrict__ sync) {
    __shared__ SMem sm;
    int t = threadIdx.x, w = t >> 6, l = t & 63;

    if (blockIdx.x < BB) {
        // ================= FPS role (R2-proven structure) =================
        __builtin_amdgcn_s_setprio(3);
        int b = blockIdx.x;
        const float* P = pos + (size_t)b * NPTS * 3;

        for (int i = t; i < NPTS; i += TPB) {
            sm.f.Pl[i] = make_float4(P[i * 3 + 0], P[i * 3 + 1], P[i * 3 + 2], 0.f);
        }
        float bval = (float)batch[(size_t)b * NPTS];
        for (int i = t; i < SS; i += TPB) batch_out[b * SS + i] = bval;

        float px[PPT], py[PPT], pz[PPT], md[PPT];
        int base = t * PPT;
#pragma unroll
        for (int j = 0; j < PPT; j++) {
            px[j] = P[(base + j) * 3 + 0];
            py[j] = P[(base + j) * 3 + 1];
            pz[j] = P[(base + j) * 3 + 2];
        }
        float c0x = P[0], c0y = P[1], c0z = P[2];
        float lm = -1.f;
#pragma unroll
        for (int j = 0; j < PPT; j++) {
            float dx = __fsub_rn(px[j], c0x);
            float dy = __fsub_rn(py[j], c0y);
            float dz = __fsub_rn(pz[j], c0z);
            md[j] = __fadd_rn(__fadd_rn(__fmul_rn(dx, dx), __fmul_rn(dy, dy)), __fmul_rn(dz, dz));
            lm = fmaxf(lm, md[j]);
        }
        if (t == 0) {
            float* qp = pos_out + (size_t)(b * SS) * 3;
            qp[0] = c0x; qp[1] = c0y; qp[2] = c0z;
        }
        __syncthreads();   // Pl ready

        for (int s = 1; s < SS; s++) {
            int jsel = 0x7FFFFFFF;
#pragma unroll
            for (int j = PPT - 1; j >= 0; j--)
                if (md[j] == lm) jsel = base + j;

            float m = lm;
            DPP_FMAX(0x111)
            DPP_FMAX(0x112)
            DPP_FMAX(0x114)
            DPP_FMAX(0x118)
            DPP_FMAX(0x142)
            DPP_FMAX(0x143)
            float wm = __uint_as_float((unsigned)__builtin_amdgcn_readlane(__float_as_uint(m), 63));

            unsigned long long mask = __ballot(lm == wm);
            int L = __ffsll((long long)mask) - 1;
            int si = __builtin_amdgcn_readlane(jsel, L);

            if (l == 0)
                sm.f.wkey[s & 1][w] = (((unsigned long long)__float_as_uint(wm)) << 32) | (~(unsigned)si);
            __syncthreads();

            const unsigned long long* wk = sm.f.wkey[s & 1];
            unsigned long long g0 = wk[0] > wk[1] ? wk[0] : wk[1];
            unsigned long long g1 = wk[2] > wk[3] ? wk[2] : wk[3];
            unsigned long long g = g0 > g1 ? g0 : g1;
            int gi = (int)(~(unsigned)g);

            float4 c = sm.f.Pl[gi];
            if (t == 0) {
                float* qp = pos_out + (size_t)(b * SS + s) * 3;
                qp[0] = c.x; qp[1] = c.y; qp[2] = c.z;
                if ((s & 63) == 63) st_rel(&sync[b * 32], (unsigned)(s + 1));
            }
#pragma unroll
            for (int j = 0; j < PPT; j++) {
                float dx = __fsub_rn(px[j], c.x);
                float dy = __fsub_rn(py[j], c.y);
                float dz = __fsub_rn(pz[j], c.z);
                float d2 = __fadd_rn(__fadd_rn(__fmul_rn(dx, dx), __fmul_rn(dy, dy)), __fmul_rn(dz, dz));
                md[j] = fminf(md[j], d2);
                lm = (j == 0) ? fmaxf(-1.f, md[0]) : fmaxf(lm, md[j]);
            }
        }
        return;
    }

    // ===================== Worker role =====================
    int wid = blockIdx.x - BB;
    unsigned* ectr = &sync[256];

    // ---- E phase: E[n][c] = x[n].W1[0:3][c] + pos[n].W1[3:6][c]
    for (int id = wid * TPB + t; id < 32768 * 64; id += NW * TPB) {
        int c = id & 63;
        int n = id >> 6;
        float x0 = x[n * 3 + 0], x1 = x[n * 3 + 1], x2 = x[n * 3 + 2];
        float p0 = pos[n * 3 + 0], p1 = pos[n * 3 + 1], p2 = pos[n * 3 + 2];
        float v = x0 * W1[0 * 64 + c] + x1 * W1[1 * 64 + c] + x2 * W1[2 * 64 + c]
                + p0 * W1[3 * 64 + c] + p1 * W1[4 * 64 + c] + p2 * W1[5 * 64 + c];
        E[(size_t)n * 64 + c] = v;
    }
    if (l == 0) __hip_atomic_fetch_add(ectr, 1u, __ATOMIC_RELEASE, __HIP_MEMORY_SCOPE_AGENT);

    // ---- stage weights (no dependency)
    for (int i = t; i < 64 * 64; i += TPB) {
        int n = i >> 6, k = i & 63;
        sm.w.W2t[(n << 6) | (k ^ ((n & 7) << 3))] = (_Float16)W2[k * 64 + n];
    }
    for (int i = t; i < 128 * 64; i += TPB) {
        int n = i >> 6, k = i & 63;
        sm.w.W3t[(n << 6) | (k ^ ((n & 7) << 3))] = (_Float16)W3[k * 128 + n];
    }
    if (t < 64) sm.w.b2s[t] = b2[t];
    if (t < 128) sm.w.b3s[t] = b3[t];

    // ---- gate: all E visible chip-wide before any mlp gather
    if (t == 0) {
        while (ld_acq(ectr) < NW * 4u) __builtin_amdgcn_s_sleep(16);
    }
    __syncthreads();

    int lhi = l >> 4, llo = l & 15;

    for (int g = wid; g < 2048; g += NW) {
        int cb = g >> 8;
        unsigned need = ((unsigned)(g & 255)) * 4u + 4u;
        if (t == 0) {
            while (ld_acq(&sync[cb * 32]) < need) __builtin_amdgcn_s_sleep(16);
        }
        __syncthreads();

        // ---------- ball: wave w handles query qi = 4g + w ----------
        {
            int qi = 4 * g + w;
            int bBase = cb * NPTS;
            const float* P = pos + (size_t)bBase * 3;
            float qx = pos_out[qi * 3 + 0], qy = pos_out[qi * 3 + 1], qz = pos_out[qi * 3 + 2];

            int total = 0;
            for (int n0 = 0; n0 < NPTS; n0 += 64) {
                int n = n0 + l;
                float xx = P[n * 3 + 0], yy = P[n * 3 + 1], zz = P[n * 3 + 2];
                float dx = __fsub_rn(qx, xx);
                float dy = __fsub_rn(qy, yy);
                float dz = __fsub_rn(qz, zz);
                float d2 = __fadd_rn(__fadd_rn(__fmul_rn(dx, dx), __fmul_rn(dy, dy)), __fmul_rn(dz, dz));
                bool in = (d2 <= 0.04f);
                unsigned long long mask = __ballot(in);
                int mypos = total + (int)__popcll(mask & ((1ull << l) - 1ull));
                if (in && mypos < CAP) { sm.w.cd2[w][mypos] = d2; sm.w.cidx[w][mypos] = n; }
                total += (int)__popcll(mask);
            }

            if (total <= KK) {
                for (int i = l; i < KK; i += 64)
                    sm.w.nbrL[w][i] = bBase + sm.w.cidx[w][i < total ? i : 0];
            } else {
                int nc = total < CAP ? total : CAP;
                unsigned long long key[8];
#pragma unroll
                for (int i = 0; i < 8; i++) {
                    int p = l + (i << 6);
                    key[i] = (p < nc)
                           ? ((((unsigned long long)__float_as_uint(sm.w.cd2[w][p])) << 12) | (unsigned)sm.w.cidx[w][p])
                           : ~0ull;
                }
                unsigned long long lo = 0, hi = ((unsigned long long)0x3D23D70Bu) << 12;
                while (lo < hi) {
                    unsigned long long mid = (lo + hi) >> 1;
                    int cnt = 0;
#pragma unroll
                    for (int i = 0; i < 8; i++) cnt += (int)__popcll(__ballot(key[i] <= mid));
                    if (cnt >= KK) hi = mid; else lo = mid + 1;
                }
                int done = 0;
#pragma unroll
                for (int i = 0; i < 8; i++) {
                    bool s2 = (key[i] <= lo);
                    unsigned long long mk = __ballot(s2);
                    int p2 = done + (int)__popcll(mk & ((1ull << l) - 1ull));
                    if (s2) sm.w.nbrL[w][p2] = bBase + (int)(key[i] & 0xFFFull);
                    done += (int)__popcll(mk);
                }
            }
        }
        __syncthreads();   // nbrL ready for all 4 queries

        // ---------- mlp: 4 queries, whole block each ----------
        for (int qq = 0; qq < 4; qq++) {
            int qi = 4 * g + qq;
            if (t < 64) {
                float qx = pos_out[qi * 3 + 0], qy = pos_out[qi * 3 + 1], qz = pos_out[qi * 3 + 2];
                sm.w.csh[t] = b1[t] - (qx * W1[3 * 64 + t] + qy * W1[4 * 64 + t] + qz * W1[5 * 64 + t]);
            }
            __syncthreads();

            half8 a2[2][2];
            int row0 = w * 32;
#pragma unroll
            for (int mt = 0; mt < 2; mt++) {
                int r = row0 + mt * 16 + llo;
                int nb = sm.w.nbrL[qq][r];
                const float* Er = E + (size_t)nb * 64;
#pragma unroll
                for (int ks = 0; ks < 2; ks++) {
                    int k0 = lhi * 8 + ks * 32;
                    f32x4 e0 = *(const f32x4*)(Er + k0);
                    f32x4 e1 = *(const f32x4*)(Er + k0 + 4);
                    f32x4 c0 = *(const f32x4*)(sm.w.csh + k0);
                    f32x4 c1 = *(const f32x4*)(sm.w.csh + k0 + 4);
                    half8 a;
#pragma unroll
                    for (int e = 0; e < 4; e++) {
                        a[e]     = (_Float16)fmaxf(e0[e] + c0[e], 0.f);
                        a[4 + e] = (_Float16)fmaxf(e1[e] + c1[e], 0.f);
                    }
                    a2[mt][ks] = a;
                }
            }

            f32x4 acc2[2][4];
#pragma unroll
            for (int mt = 0; mt < 2; mt++)
#pragma unroll
                for (int nt = 0; nt < 4; nt++) acc2[mt][nt] = (f32x4){0.f, 0.f, 0.f, 0.f};
#pragma unroll
            for (int ks = 0; ks < 2; ks++) {
                int k0 = lhi * 8 + ks * 32;
#pragma unroll
                for (int nt = 0; nt < 4; nt++) {
                    int n = nt * 16 + llo;
                    half8 bf = *(const half8*)&sm.w.W2t[(n << 6) | (k0 ^ ((n & 7) << 3))];
#pragma unroll
                    for (int mt = 0; mt < 2; mt++)
                        acc2[mt][nt] = __builtin_amdgcn_mfma_f32_16x16x32_f16(a2[mt][ks], bf, acc2[mt][nt], 0, 0, 0);
                }
            }

            _Float16* hb = sm.w.h2buf[w];
#pragma unroll
            for (int mt = 0; mt < 2; mt++)
#pragma unroll
                for (int nt = 0; nt < 4; nt++)
#pragma unroll
                    for (int r = 0; r < 4; r++) {
                        int lr = mt * 16 + lhi * 4 + r;
                        int n = nt * 16 + llo;
                        float v = fmaxf(acc2[mt][nt][r] + sm.w.b2s[n], 0.f);
                        hb[(lr << 6) | (n ^ ((lr & 7) << 3))] = (_Float16)v;
                    }

            half8 a3[2][2];
#pragma unroll
            for (int mt = 0; mt < 2; mt++)
#pragma unroll
                for (int ks = 0; ks < 2; ks++) {
                    int lr = mt * 16 + llo;
                    int k0 = lhi * 8 + ks * 32;
                    a3[mt][ks] = *(const half8*)&hb[(lr << 6) | (k0 ^ ((lr & 7) << 3))];
                }
            f32x4 acc3[2][8];
#pragma unroll
            for (int mt = 0; mt < 2; mt++)
#pragma unroll
                for (int nt = 0; nt < 8; nt++) acc3[mt][nt] = (f32x4){0.f, 0.f, 0.f, 0.f};
#pragma unroll
            for (int ks = 0; ks < 2; ks++) {
                int k0 = lhi * 8 + ks * 32;
#pragma unroll
                for (int nt = 0; nt < 8; nt++) {
                    int n = nt * 16 + llo;
                    half8 bf = *(const half8*)&sm.w.W3t[(n << 6) | (k0 ^ ((n & 7) << 3))];
#pragma unroll
                    for (int mt = 0; mt < 2; mt++)
                        acc3[mt][nt] = __builtin_amdgcn_mfma_f32_16x16x32_f16(a3[mt][ks], bf, acc3[mt][nt], 0, 0, 0);
                }
            }

#pragma unroll
            for (int nt = 0; nt < 8; nt++) {
                float m = acc3[0][nt][0];
#pragma unroll
                for (int r = 1; r < 4; r++) m = fmaxf(m, acc3[0][nt][r]);
#pragma unroll
                for (int r = 0; r < 4; r++) m = fmaxf(m, acc3[1][nt][r]);
                m = fmaxf(m, __shfl_xor(m, 16));
                m = fmaxf(m, __shfl_xor(m, 32));
                if (l < 16) sm.w.cpart[w][nt * 16 + l] = m;
            }
            __syncthreads();
            if (t < 128) {
                float v = fmaxf(fmaxf(sm.w.cpart[0][t], sm.w.cpart[1][t]),
                                fmaxf(sm.w.cpart[2][t], sm.w.cpart[3][t])) + sm.w.b3s[t];
                xout[(size_t)qi * 128 + t] = v;
            }
            __syncthreads();
        }
        __syncthreads();   // cd2/cidx/nbrL reuse in next group
    }
}

// ---------------------------------------------------------------------------
extern "C" void kernel_launch(void* const* d_in, const int* in_sizes, int n_in,
                              void* d_out, int out_size, void* d_ws, size_t ws_size,
                              hipStream_t stream) {
    const float* x   = (const float*)d_in[0];
    const float* pos = (const float*)d_in[1];
    const float* W1  = (const float*)d_in[2];
    const float* b1  = (const float*)d_in[3];
    const float* W2  = (const float*)d_in[4];
    const float* b2  = (const float*)d_in[5];
    const float* W3  = (const float*)d_in[6];
    const float* b3  = (const float*)d_in[7];
    const int* batch = (const int*)d_in[8];

    float* xout      = (float*)d_out;                       // [8192][128]
    float* pos_out   = xout + (size_t)BB * SS * 128;        // [8192][3]
    float* batch_out = pos_out + (size_t)BB * SS * 3;       // [8192]

    float* E = (float*)d_ws;                                // 32768*64 f32 = 8 MB
    unsigned* sync = (unsigned*)((char*)d_ws + (size_t)32768 * 64 * 4);
    // sync layout: prog[b] at sync[b*32] (128B apart), ectr at sync[256]
    hipMemsetAsync(sync, 0, 4096, stream);

    fused_kernel<<<dim3(BB + NW), dim3(TPB), 0, stream>>>(
        pos, batch, x, W1, b1, W2, b2, W3, b3, E, pos_out, batch_out, xout, sync);
}

// Round 7
// 619.168 us; speedup vs baseline: 1.3492x; 1.3492x over previous
//
#include <hip/hip_runtime.h>
#include <hip/hip_fp16.h>

#define BB    8
#define NPTS  4096
#define SS    1024
#define KK    128
#define CAP   512
#define NW    248          // worker blocks (8 + 248 = 256 = #CUs)
#define TPB   256
#define PPT   16

typedef _Float16 half8 __attribute__((ext_vector_type(8)));
typedef float    f32x4 __attribute__((ext_vector_type(4)));

// ---------------------------------------------------------------------------
// Fused streaming kernel, R7 (= R6 with compile fix: ticket-position variable
// renamed so it no longer shadows the `pos` pointer parameter).
//   Dedicated-CU placement + work-stealing:
//   R5 post-mortem: static group assignment made worker wid's FIRST group
//   unlock at (wid/256)*564us -> worker 247 idled ~544us then ran ~300us of
//   groups serially (measured 849us fits). Fix: global ticket counter in
//   unlock order (position-major: k -> posi=k>>3, cloud=k&7), so workers
//   always grab the earliest-unlocking remaining group. Tail after FPS's
//   last publish: ~128 groups over 248 idle workers = one each (~38us).
//   LDS padded to 84KB keeps 1 block/CU: FPS blocks own their CUs (solo
//   564us pace), workers own theirs.
// ---------------------------------------------------------------------------

struct __align__(16) FpsSm {
    float4 Pl[NPTS];                       // 64 KB point cache
    unsigned long long wkey[2][4];         // parity-double-buffered
};
struct __align__(16) WkSm {
    float cd2[4][CAP];
    int   cidx[4][CAP];
    int   nbrL[4][KK];                     // neighbor ids (global), LDS-only
    _Float16 W2t[64 * 64];                 // [n][k] swizzled
    _Float16 W3t[128 * 64];                // [n][k] swizzled
    _Float16 h2buf[4][32 * 64];
    float csh[64];
    float cpart[4][128];
    float b2s[64];
    float b3s[128];
    unsigned tick;                         // work-stealing ticket broadcast
};
union __align__(16) SMem {
    FpsSm f;
    WkSm  w;
    char  pad[84 * 1024];                  // force 1 block/CU (160KB LDS / 84KB)
};

__device__ __forceinline__ void st_rel(unsigned* p, unsigned v) {
    __hip_atomic_store(p, v, __ATOMIC_RELEASE, __HIP_MEMORY_SCOPE_AGENT);
}
__device__ __forceinline__ unsigned ld_acq(unsigned* p) {
    return __hip_atomic_load(p, __ATOMIC_ACQUIRE, __HIP_MEMORY_SCOPE_AGENT);
}

// one DPP fmax step (old preserved on disabled lanes => identity for max)
#define DPP_FMAX(CTRL)                                                                  \
    {                                                                                   \
        unsigned o = (unsigned)__builtin_amdgcn_update_dpp(                             \
            (int)__float_as_uint(m), (int)__float_as_uint(m), CTRL, 0xF, 0xF, false);   \
        m = fmaxf(m, __uint_as_float(o));                                               \
    }

__global__ __launch_bounds__(TPB) void fused_kernel(const float* __restrict__ pos,
                                                    const int* __restrict__ batch,
                                                    const float* __restrict__ x,
                                                    const float* __restrict__ W1,
                                                    const float* __restrict__ b1,
                                                    const float* __restrict__ W2,
                                                    const float* __restrict__ b2,
                                                    const float* __restrict__ W3,
                                                    const float* __restrict__ b3,
                                                    float* __restrict__ E,
                                                    float* __restrict__ pos_out,
                                                    float* __restrict__ batch_out,
                                                    float* __restrict__ xout,
                                                    unsigned* __restrict__ sync) {
    __shared__ SMem sm;
    int t = threadIdx.x, w = t >> 6, l = t & 63;

    if (blockIdx.x < BB) {
        // ================= FPS role (R2-proven structure) =================
        __builtin_amdgcn_s_setprio(3);
        int b = blockIdx.x;
        const float* P = pos + (size_t)b * NPTS * 3;

        for (int i = t; i < NPTS; i += TPB) {
            sm.f.Pl[i] = make_float4(P[i * 3 + 0], P[i * 3 + 1], P[i * 3 + 2], 0.f);
        }
        float bval = (float)batch[(size_t)b * NPTS];
        for (int i = t; i < SS; i += TPB) batch_out[b * SS + i] = bval;

        float px[PPT], py[PPT], pz[PPT], md[PPT];
        int base = t * PPT;
#pragma unroll
        for (int j = 0; j < PPT; j++) {
            px[j] = P[(base + j) * 3 + 0];
            py[j] = P[(base + j) * 3 + 1];
            pz[j] = P[(base + j) * 3 + 2];
        }
        float c0x = P[0], c0y = P[1], c0z = P[2];
        float lm = -1.f;
#pragma unroll
        for (int j = 0; j < PPT; j++) {
            float dx = __fsub_rn(px[j], c0x);
            float dy = __fsub_rn(py[j], c0y);
            float dz = __fsub_rn(pz[j], c0z);
            md[j] = __fadd_rn(__fadd_rn(__fmul_rn(dx, dx), __fmul_rn(dy, dy)), __fmul_rn(dz, dz));
            lm = fmaxf(lm, md[j]);
        }
        if (t == 0) {
            float* qp = pos_out + (size_t)(b * SS) * 3;
            qp[0] = c0x; qp[1] = c0y; qp[2] = c0z;
        }
        __syncthreads();   // Pl ready

        for (int s = 1; s < SS; s++) {
            int jsel = 0x7FFFFFFF;
#pragma unroll
            for (int j = PPT - 1; j >= 0; j--)
                if (md[j] == lm) jsel = base + j;

            float m = lm;
            DPP_FMAX(0x111)
            DPP_FMAX(0x112)
            DPP_FMAX(0x114)
            DPP_FMAX(0x118)
            DPP_FMAX(0x142)
            DPP_FMAX(0x143)
            float wm = __uint_as_float((unsigned)__builtin_amdgcn_readlane(__float_as_uint(m), 63));

            unsigned long long mask = __ballot(lm == wm);
            int L = __ffsll((long long)mask) - 1;
            int si = __builtin_amdgcn_readlane(jsel, L);

            if (l == 0)
                sm.f.wkey[s & 1][w] = (((unsigned long long)__float_as_uint(wm)) << 32) | (~(unsigned)si);
            __syncthreads();

            const unsigned long long* wk = sm.f.wkey[s & 1];
            unsigned long long g0 = wk[0] > wk[1] ? wk[0] : wk[1];
            unsigned long long g1 = wk[2] > wk[3] ? wk[2] : wk[3];
            unsigned long long g = g0 > g1 ? g0 : g1;
            int gi = (int)(~(unsigned)g);

            float4 c = sm.f.Pl[gi];
            if (t == 0) {
                float* qp = pos_out + (size_t)(b * SS + s) * 3;
                qp[0] = c.x; qp[1] = c.y; qp[2] = c.z;
                if ((s & 63) == 63) st_rel(&sync[b * 32], (unsigned)(s + 1));
            }
#pragma unroll
            for (int j = 0; j < PPT; j++) {
                float dx = __fsub_rn(px[j], c.x);
                float dy = __fsub_rn(py[j], c.y);
                float dz = __fsub_rn(pz[j], c.z);
                float d2 = __fadd_rn(__fadd_rn(__fmul_rn(dx, dx), __fmul_rn(dy, dy)), __fmul_rn(dz, dz));
                md[j] = fminf(md[j], d2);
                lm = (j == 0) ? fmaxf(-1.f, md[0]) : fmaxf(lm, md[j]);
            }
        }
        return;
    }

    // ===================== Worker role =====================
    int wid = blockIdx.x - BB;
    unsigned* ectr = &sync[256];
    unsigned* qctr = &sync[260];

    // ---- E phase: E[n][c] = x[n].W1[0:3][c] + pos[n].W1[3:6][c]
    for (int id = wid * TPB + t; id < 32768 * 64; id += NW * TPB) {
        int c = id & 63;
        int n = id >> 6;
        float x0 = x[n * 3 + 0], x1 = x[n * 3 + 1], x2 = x[n * 3 + 2];
        float p0 = pos[n * 3 + 0], p1 = pos[n * 3 + 1], p2 = pos[n * 3 + 2];
        float v = x0 * W1[0 * 64 + c] + x1 * W1[1 * 64 + c] + x2 * W1[2 * 64 + c]
                + p0 * W1[3 * 64 + c] + p1 * W1[4 * 64 + c] + p2 * W1[5 * 64 + c];
        E[(size_t)n * 64 + c] = v;
    }
    if (l == 0) __hip_atomic_fetch_add(ectr, 1u, __ATOMIC_RELEASE, __HIP_MEMORY_SCOPE_AGENT);

    // ---- stage weights (no dependency)
    for (int i = t; i < 64 * 64; i += TPB) {
        int n = i >> 6, k = i & 63;
        sm.w.W2t[(n << 6) | (k ^ ((n & 7) << 3))] = (_Float16)W2[k * 64 + n];
    }
    for (int i = t; i < 128 * 64; i += TPB) {
        int n = i >> 6, k = i & 63;
        sm.w.W3t[(n << 6) | (k ^ ((n & 7) << 3))] = (_Float16)W3[k * 128 + n];
    }
    if (t < 64) sm.w.b2s[t] = b2[t];
    if (t < 128) sm.w.b3s[t] = b3[t];

    // ---- gate: all E visible chip-wide before any mlp gather
    if (t == 0) {
        while (ld_acq(ectr) < NW * 4u) __builtin_amdgcn_s_sleep(16);
    }
    __syncthreads();

    int lhi = l >> 4, llo = l & 15;

    // ---- work-stealing over 2048 groups in unlock order:
    //      ticket k -> posi = k>>3 (0..255), cloud = k&7. Group = 4 queries.
    while (true) {
        if (t == 0) {
            unsigned k = __hip_atomic_fetch_add(qctr, 1u, __ATOMIC_RELAXED, __HIP_MEMORY_SCOPE_AGENT);
            sm.w.tick = k;
        }
        __syncthreads();
        unsigned k = sm.w.tick;
        if (k >= 2048u) break;
        int posi = (int)(k >> 3);
        int cb   = (int)(k & 7u);
        int q0g = cb * SS + posi * 4;                // first query of this group
        unsigned need = (unsigned)(posi * 4 + 4);
        if (t == 0) {
            while (ld_acq(&sync[cb * 32]) < need) __builtin_amdgcn_s_sleep(16);
        }
        __syncthreads();

        // ---------- ball: wave w handles query qi = q0g + w ----------
        {
            int qi = q0g + w;
            int bBase = cb * NPTS;
            const float* P = pos + (size_t)bBase * 3;
            float qx = pos_out[qi * 3 + 0], qy = pos_out[qi * 3 + 1], qz = pos_out[qi * 3 + 2];

            int total = 0;
            for (int n0 = 0; n0 < NPTS; n0 += 64) {
                int n = n0 + l;
                float xx = P[n * 3 + 0], yy = P[n * 3 + 1], zz = P[n * 3 + 2];
                float dx = __fsub_rn(qx, xx);
                float dy = __fsub_rn(qy, yy);
                float dz = __fsub_rn(qz, zz);
                float d2 = __fadd_rn(__fadd_rn(__fmul_rn(dx, dx), __fmul_rn(dy, dy)), __fmul_rn(dz, dz));
                bool in = (d2 <= 0.04f);
                unsigned long long mask = __ballot(in);
                int mypos = total + (int)__popcll(mask & ((1ull << l) - 1ull));
                if (in && mypos < CAP) { sm.w.cd2[w][mypos] = d2; sm.w.cidx[w][mypos] = n; }
                total += (int)__popcll(mask);
            }

            if (total <= KK) {
                for (int i = l; i < KK; i += 64)
                    sm.w.nbrL[w][i] = bBase + sm.w.cidx[w][i < total ? i : 0];
            } else {
                int nc = total < CAP ? total : CAP;
                unsigned long long key[8];
#pragma unroll
                for (int i = 0; i < 8; i++) {
                    int p = l + (i << 6);
                    key[i] = (p < nc)
                           ? ((((unsigned long long)__float_as_uint(sm.w.cd2[w][p])) << 12) | (unsigned)sm.w.cidx[w][p])
                           : ~0ull;
                }
                unsigned long long lo = 0, hi = ((unsigned long long)0x3D23D70Bu) << 12;
                while (lo < hi) {
                    unsigned long long mid = (lo + hi) >> 1;
                    int cnt = 0;
#pragma unroll
                    for (int i = 0; i < 8; i++) cnt += (int)__popcll(__ballot(key[i] <= mid));
                    if (cnt >= KK) hi = mid; else lo = mid + 1;
                }
                int done = 0;
#pragma unroll
                for (int i = 0; i < 8; i++) {
                    bool s2 = (key[i] <= lo);
                    unsigned long long mk = __ballot(s2);
                    int p2 = done + (int)__popcll(mk & ((1ull << l) - 1ull));
                    if (s2) sm.w.nbrL[w][p2] = bBase + (int)(key[i] & 0xFFFull);
                    done += (int)__popcll(mk);
                }
            }
        }
        __syncthreads();   // nbrL ready for all 4 queries

        // ---------- mlp: 4 queries, whole block each ----------
        for (int qq = 0; qq < 4; qq++) {
            int qi = q0g + qq;
            if (t < 64) {
                float qx = pos_out[qi * 3 + 0], qy = pos_out[qi * 3 + 1], qz = pos_out[qi * 3 + 2];
                sm.w.csh[t] = b1[t] - (qx * W1[3 * 64 + t] + qy * W1[4 * 64 + t] + qz * W1[5 * 64 + t]);
            }
            __syncthreads();

            half8 a2[2][2];
            int row0 = w * 32;
#pragma unroll
            for (int mt = 0; mt < 2; mt++) {
                int r = row0 + mt * 16 + llo;
                int nb = sm.w.nbrL[qq][r];
                const float* Er = E + (size_t)nb * 64;
#pragma unroll
                for (int ks = 0; ks < 2; ks++) {
                    int k0 = lhi * 8 + ks * 32;
                    f32x4 e0 = *(const f32x4*)(Er + k0);
                    f32x4 e1 = *(const f32x4*)(Er + k0 + 4);
                    f32x4 c0 = *(const f32x4*)(sm.w.csh + k0);
                    f32x4 c1 = *(const f32x4*)(sm.w.csh + k0 + 4);
                    half8 a;
#pragma unroll
                    for (int e = 0; e < 4; e++) {
                        a[e]     = (_Float16)fmaxf(e0[e] + c0[e], 0.f);
                        a[4 + e] = (_Float16)fmaxf(e1[e] + c1[e], 0.f);
                    }
                    a2[mt][ks] = a;
                }
            }

            f32x4 acc2[2][4];
#pragma unroll
            for (int mt = 0; mt < 2; mt++)
#pragma unroll
                for (int nt = 0; nt < 4; nt++) acc2[mt][nt] = (f32x4){0.f, 0.f, 0.f, 0.f};
#pragma unroll
            for (int ks = 0; ks < 2; ks++) {
                int k0 = lhi * 8 + ks * 32;
#pragma unroll
                for (int nt = 0; nt < 4; nt++) {
                    int n = nt * 16 + llo;
                    half8 bf = *(const half8*)&sm.w.W2t[(n << 6) | (k0 ^ ((n & 7) << 3))];
#pragma unroll
                    for (int mt = 0; mt < 2; mt++)
                        acc2[mt][nt] = __builtin_amdgcn_mfma_f32_16x16x32_f16(a2[mt][ks], bf, acc2[mt][nt], 0, 0, 0);
                }
            }

            _Float16* hb = sm.w.h2buf[w];
#pragma unroll
            for (int mt = 0; mt < 2; mt++)
#pragma unroll
                for (int nt = 0; nt < 4; nt++)
#pragma unroll
                    for (int r = 0; r < 4; r++) {
                        int lr = mt * 16 + lhi * 4 + r;
                        int n = nt * 16 + llo;
                        float v = fmaxf(acc2[mt][nt][r] + sm.w.b2s[n], 0.f);
                        hb[(lr << 6) | (n ^ ((lr & 7) << 3))] = (_Float16)v;
                    }

            half8 a3[2][2];
#pragma unroll
            for (int mt = 0; mt < 2; mt++)
#pragma unroll
                for (int ks = 0; ks < 2; ks++) {
                    int lr = mt * 16 + llo;
                    int k0 = lhi * 8 + ks * 32;
                    a3[mt][ks] = *(const half8*)&hb[(lr << 6) | (k0 ^ ((lr & 7) << 3))];
                }
            f32x4 acc3[2][8];
#pragma unroll
            for (int mt = 0; mt < 2; mt++)
#pragma unroll
                for (int nt = 0; nt < 8; nt++) acc3[mt][nt] = (f32x4){0.f, 0.f, 0.f, 0.f};
#pragma unroll
            for (int ks = 0; ks < 2; ks++) {
                int k0 = lhi * 8 + ks * 32;
#pragma unroll
                for (int nt = 0; nt < 8; nt++) {
                    int n = nt * 16 + llo;
                    half8 bf = *(const half8*)&sm.w.W3t[(n << 6) | (k0 ^ ((n & 7) << 3))];
#pragma unroll
                    for (int mt = 0; mt < 2; mt++)
                        acc3[mt][nt] = __builtin_amdgcn_mfma_f32_16x16x32_f16(a3[mt][ks], bf, acc3[mt][nt], 0, 0, 0);
                }
            }

#pragma unroll
            for (int nt = 0; nt < 8; nt++) {
                float m = acc3[0][nt][0];
#pragma unroll
                for (int r = 1; r < 4; r++) m = fmaxf(m, acc3[0][nt][r]);
#pragma unroll
                for (int r = 0; r < 4; r++) m = fmaxf(m, acc3[1][nt][r]);
                m = fmaxf(m, __shfl_xor(m, 16));
                m = fmaxf(m, __shfl_xor(m, 32));
                if (l < 16) sm.w.cpart[w][nt * 16 + l] = m;
            }
            __syncthreads();
            if (t < 128) {
                float v = fmaxf(fmaxf(sm.w.cpart[0][t], sm.w.cpart[1][t]),
                                fmaxf(sm.w.cpart[2][t], sm.w.cpart[3][t])) + sm.w.b3s[t];
                xout[(size_t)qi * 128 + t] = v;
            }
            __syncthreads();
        }
        __syncthreads();   // cd2/cidx/nbrL/tick reuse in next iteration
    }
}

// ---------------------------------------------------------------------------
extern "C" void kernel_launch(void* const* d_in, const int* in_sizes, int n_in,
                              void* d_out, int out_size, void* d_ws, size_t ws_size,
                              hipStream_t stream) {
    const float* x   = (const float*)d_in[0];
    const float* pos = (const float*)d_in[1];
    const float* W1  = (const float*)d_in[2];
    const float* b1  = (const float*)d_in[3];
    const float* W2  = (const float*)d_in[4];
    const float* b2  = (const float*)d_in[5];
    const float* W3  = (const float*)d_in[6];
    const float* b3  = (const float*)d_in[7];
    const int* batch = (const int*)d_in[8];

    float* xout      = (float*)d_out;                       // [8192][128]
    float* pos_out   = xout + (size_t)BB * SS * 128;        // [8192][3]
    float* batch_out = pos_out + (size_t)BB * SS * 3;       // [8192]

    float* E = (float*)d_ws;                                // 32768*64 f32 = 8 MB
    unsigned* sync = (unsigned*)((char*)d_ws + (size_t)32768 * 64 * 4);
    // sync layout: prog[b] at sync[b*32] (128B apart), ectr at sync[256],
    //              group ticket counter at sync[260]
    (void)hipMemsetAsync(sync, 0, 4096, stream);

    fused_kernel<<<dim3(BB + NW), dim3(TPB), 0, stream>>>(
        pos, batch, x, W1, b1, W2, b2, W3, b3, E, pos_out, batch_out, xout, sync);
}